// Round 3
// baseline (598.283 us; speedup 1.0000x reference)
//
#include <hip/hip_runtime.h>
#include <stdint.h>
#include <stddef.h>

#define DM 1024
#define SEQ 4096
#define NB 4
#define NTOK (NB*SEQ)

typedef __attribute__((ext_vector_type(8))) short s16x8;
typedef __attribute__((ext_vector_type(4))) float f32x4;

__device__ __forceinline__ unsigned short f2bf(float f) {
  unsigned int u = __float_as_uint(f);
  u += 0x7FFFu + ((u >> 16) & 1u);   // round-to-nearest-even
  return (unsigned short)(u >> 16);
}

__device__ __forceinline__ f32x4 mfma16(s16x8 a, s16x8 b, f32x4 c) {
  return __builtin_amdgcn_mfma_f32_16x16x32_bf16(a, b, c, 0, 0, 0);
}

__device__ __forceinline__ void gload16(const void* g, void* l) {
  __builtin_amdgcn_global_load_lds((const __attribute__((address_space(1))) unsigned int*)g,
                                   (__attribute__((address_space(3))) unsigned int*)l, 16, 0, 0);
}

template<int N> __device__ __forceinline__ void vmcnt() {
  asm volatile("s_waitcnt vmcnt(%0)" :: "n"(N) : "memory");
}
__device__ __forceinline__ void rawbar() {
  asm volatile("s_barrier" ::: "memory");
}

// ---------------- kernel 1: f32 -> bf16 bulk convert ----------------
__global__ void k_conv(const float* __restrict__ s, unsigned short* __restrict__ d, int n8) {
  int i = blockIdx.x * blockDim.x + threadIdx.x;
  int st = gridDim.x * blockDim.x;
  for (; i < n8; i += st) {
    const f32x4* sp = (const f32x4*)s + (size_t)i * 2;
    f32x4 a = sp[0], b = sp[1];
    s16x8 o;
    o[0] = (short)f2bf(a[0]); o[1] = (short)f2bf(a[1]);
    o[2] = (short)f2bf(a[2]); o[3] = (short)f2bf(a[3]);
    o[4] = (short)f2bf(b[0]); o[5] = (short)f2bf(b[1]);
    o[6] = (short)f2bf(b[2]); o[7] = (short)f2bf(b[3]);
    *((s16x8*)d + i) = o;
  }
}

// ============ deep-pipelined GEMM core: C = A @ B^T (both k-major) ============
// BN=256, BK=32, 8 waves (2M x 4N), 3 LDS buffers, counted vmcnt (never 0 in
// steady state), raw s_barrier, XOR-swizzled LDS (slot = k8 ^ ((row>>1)&3)).
// Schedule: compute tile t from buf t%3; stage tile t+2 into buf (t+2)%3
// (write-safe: that buf was last read at tile t-1, barrier-separated).
// vmcnt(LPT) before the last mid-phase barrier of tile t retires tile t+1's
// loads in ALL waves before anyone reads them (cross-wave safety via barrier).
// EPI: 0 = bf16 out + bias; 1 = fp16 out * scale; 2 = f32 out.
template<int KD, int BM, int EPI>
__device__ __forceinline__ void gemm8p(
    const unsigned short* __restrict__ A, const unsigned short* __restrict__ B,
    void* __restrict__ outp, int ldc, const float* __restrict__ bias, float scale,
    int mbase, int nbase)
{
  constexpr int NT  = KD / 32;        // K tiles
  constexpr int PH  = BM / 128;       // phases per tile (2 for BM=256, 1 for BM=128)
  constexpr int WR  = BM / 2;         // rows per wave
  constexpr int MR  = WR / 16;        // row frags per wave (8 or 4)
  constexpr int AL  = BM * 32;        // A tile elems
  constexpr int LJA = BM / 128;       // A loads per thread per tile (2 or 1)
  constexpr int LPT = LJA + 2;        // total loads per thread per tile

  __shared__ unsigned short lA[3][AL];
  __shared__ unsigned short lB[3][256 * 32];

  const int tid = threadIdx.x, lane = tid & 63, wid = tid >> 6;
  const int wr = wid >> 2, wc = wid & 3;
  const int l15 = lane & 15, lg = lane >> 4;

  // staging source element offsets (pre-swizzled so linear LDS dest yields
  // swizzled layout; rule #21: inverse-swz source + swz read)
  int aSrc[LJA], bSrc[2];
  #pragma unroll
  for (int j = 0; j < LJA; j++) {
    int s = j * 512 + wid * 64 + lane;
    int row = s >> 2, k8 = (s & 3) ^ ((row >> 1) & 3);
    aSrc[j] = (mbase + row) * KD + k8 * 8;
  }
  #pragma unroll
  for (int j = 0; j < 2; j++) {
    int s = j * 512 + wid * 64 + lane;
    int row = s >> 2, k8 = (s & 3) ^ ((row >> 1) & 3);
    bSrc[j] = (nbase + row) * KD + k8 * 8;
  }

  // swizzled ds_read offsets (ushort units)
  int aOff[MR], bOff[4];
  #pragma unroll
  for (int m = 0; m < MR; m++) {
    int row = wr * WR + m * 16 + l15;
    aOff[m] = row * 32 + ((lg ^ ((row >> 1) & 3)) * 8);
  }
  #pragma unroll
  for (int n = 0; n < 4; n++) {
    int row = wc * 64 + n * 16 + l15;
    bOff[n] = row * 32 + ((lg ^ ((row >> 1) & 3)) * 8);
  }

  auto stA = [&](int c2, int kt, int j) {
    gload16(A + (size_t)aSrc[j] + kt * 32, &lA[c2][(j * 512 + wid * 64) * 8]);
  };
  auto stB = [&](int c2, int kt, int j) {
    gload16(B + (size_t)bSrc[j] + kt * 32, &lB[c2][(j * 512 + wid * 64) * 8]);
  };

  f32x4 acc[MR][4];
  #pragma unroll
  for (int m = 0; m < MR; m++)
    #pragma unroll
    for (int n = 0; n < 4; n++) { acc[m][n][0]=0.f; acc[m][n][1]=0.f; acc[m][n][2]=0.f; acc[m][n][3]=0.f; }

  // prologue: stage tiles 0 and 1
  #pragma unroll
  for (int j = 0; j < LJA; j++) stA(0, 0, j);
  stB(0, 0, 0); stB(0, 0, 1);
  #pragma unroll
  for (int j = 0; j < LJA; j++) stA(1, 1, j);
  stB(1, 1, 0); stB(1, 1, 1);
  vmcnt<LPT>();          // tile 0 landed (outstanding 2*LPT -> LPT)
  rawbar();

  int cur = 0;
  for (int t = 0; t < NT; t++) {
    int c2 = cur + 2; if (c2 >= 3) c2 -= 3;   // buffer for tile t+2
    #pragma unroll
    for (int ph = 0; ph < PH; ph++) {
      s16x8 af[4], bf[4];
      #pragma unroll
      for (int i = 0; i < 4; i++)
        af[i] = *(const s16x8*)(&lA[cur][0] + aOff[ph * 4 + i]);
      #pragma unroll
      for (int n = 0; n < 4; n++)
        bf[n] = *(const s16x8*)(&lB[cur][0] + bOff[n]);

      if (t + 2 < NT) {
        if (PH == 2) {
          if (ph == 0) { stA(c2, t + 2, 0); if (LJA > 1) stA(c2, t + 2, LJA - 1); }
          else         { stB(c2, t + 2, 0); stB(c2, t + 2, 1); }
        } else {
          stA(c2, t + 2, 0); stB(c2, t + 2, 0); stB(c2, t + 2, 1);
        }
      }
      if (ph == PH - 1) {
        if (t + 2 < NT)      vmcnt<LPT>();   // retire tile t+1's loads (counted, not 0)
        else if (t + 1 < NT) vmcnt<0>();     // epilogue drain (once)
      }
      rawbar();                               // all waves' vmcnt done -> t+1 data visible
      __builtin_amdgcn_s_setprio(1);
      #pragma unroll
      for (int i = 0; i < 4; i++)
        #pragma unroll
        for (int n = 0; n < 4; n++)
          acc[ph * 4 + i][n] = mfma16(af[i], bf[n], acc[ph * 4 + i][n]);
      __builtin_amdgcn_s_setprio(0);
      rawbar();
    }
    cur++; if (cur >= 3) cur = 0;
  }

  // epilogue
  #pragma unroll
  for (int n = 0; n < 4; n++) {
    int col = nbase + wc * 64 + n * 16 + l15;
    float bb = (EPI == 0) ? bias[col] : 0.f;
    #pragma unroll
    for (int m = 0; m < MR; m++) {
      #pragma unroll
      for (int r = 0; r < 4; r++) {
        int row = mbase + wr * WR + m * 16 + lg * 4 + r;
        float v = acc[m][n][r];
        if (EPI == 0) {
          ((unsigned short*)outp)[(size_t)row * ldc + col] = f2bf(v + bb);
        } else if (EPI == 1) {
          _Float16 h = (_Float16)(v * scale);
          ((unsigned short*)outp)[(size_t)row * ldc + col] = __builtin_bit_cast(unsigned short, h);
        } else {
          ((float*)outp)[(size_t)row * ldc + col] = v;
        }
      }
    }
  }
}

// ---------------- kernel 2: fused QKV projection ----------------
__global__ __launch_bounds__(512, 2) void k_qkv(
    const unsigned short* __restrict__ xb, const unsigned short* __restrict__ wb,
    const float* __restrict__ b0, const float* __restrict__ b1, const float* __restrict__ b2,
    unsigned short* __restrict__ qo, unsigned short* __restrict__ ko, unsigned short* __restrict__ vo)
{
  const int z = blockIdx.z;
  gemm8p<DM, 256, 0>(xb, wb + (size_t)z * DM * DM,
                     (z == 0) ? qo : (z == 1) ? ko : vo, DM,
                     (z == 0) ? b0 : (z == 1) ? b1 : b2, 0.f,
                     blockIdx.y * 256, blockIdx.x * 256);
}

// ---------------- kernel 3: V -> V^T transpose (per batch) ----------------
__global__ void k_transpose(const unsigned short* __restrict__ v, unsigned short* __restrict__ vt) {
  __shared__ unsigned short t[64][65];
  const int b = blockIdx.z;
  const int rbase = blockIdx.x * 64;   // token dim
  const int cbase = blockIdx.y * 64;   // channel dim
  const unsigned short* vb = v + (size_t)b * SEQ * DM;
  unsigned short* vtb = vt + (size_t)b * DM * SEQ;
  const int tid = threadIdx.x;
  #pragma unroll
  for (int it = 0; it < 16; it++) {
    int idx = it * 256 + tid;
    int r = idx >> 6, c = idx & 63;
    t[r][c] = vb[(size_t)(rbase + r) * DM + cbase + c];
  }
  __syncthreads();
  #pragma unroll
  for (int it = 0; it < 16; it++) {
    int idx = it * 256 + tid;
    int oc = idx >> 6, ot = idx & 63;
    vtb[(size_t)(cbase + oc) * SEQ + rbase + ot] = t[ot][oc];
  }
}

// ---------------- kernel 4: scores GEMM  S = Q @ K^T * scale -> fp16 ----------------
__global__ __launch_bounds__(512, 2) void k_sgemm(
    const unsigned short* __restrict__ qb, const unsigned short* __restrict__ kb,
    unsigned short* __restrict__ sc0, unsigned short* __restrict__ sc1, int bb)
{
  const int z = blockIdx.z;
  gemm8p<DM, 256, 1>(qb + (size_t)(bb + z) * SEQ * DM, kb + (size_t)(bb + z) * SEQ * DM,
                     z ? sc1 : sc0, SEQ, nullptr, 0.03125f,
                     blockIdx.y * 256, blockIdx.x * 256);
}

// ---------------- kernel 5: row softmax, in-place fp16 -> normalized bf16 ----------------
__global__ __launch_bounds__(256) void k_softmax(unsigned short* __restrict__ sc0,
                                                 unsigned short* __restrict__ sc1) {
  unsigned short* sc = blockIdx.z ? sc1 : sc0;
  const int row = blockIdx.x * 4 + (threadIdx.x >> 6);
  const int lane = threadIdx.x & 63;
  unsigned short* rp = sc + (size_t)row * SEQ + lane * 8;

  s16x8 v[8];
  #pragma unroll
  for (int j = 0; j < 8; j++) v[j] = *(const s16x8*)(rp + (size_t)j * 512);

  float f[64];
  float m = -1e30f;
  #pragma unroll
  for (int j = 0; j < 8; j++)
    #pragma unroll
    for (int t = 0; t < 8; t++) {
      float x = (float)__builtin_bit_cast(_Float16, (unsigned short)v[j][t]);
      f[j * 8 + t] = x;
      m = fmaxf(m, x);
    }
  m = fmaxf(m, __shfl_xor(m, 1));  m = fmaxf(m, __shfl_xor(m, 2));
  m = fmaxf(m, __shfl_xor(m, 4));  m = fmaxf(m, __shfl_xor(m, 8));
  m = fmaxf(m, __shfl_xor(m, 16)); m = fmaxf(m, __shfl_xor(m, 32));

  float s = 0.f;
  #pragma unroll
  for (int i = 0; i < 64; i++) { f[i] = __expf(f[i] - m); s += f[i]; }
  s += __shfl_xor(s, 1);  s += __shfl_xor(s, 2);  s += __shfl_xor(s, 4);
  s += __shfl_xor(s, 8);  s += __shfl_xor(s, 16); s += __shfl_xor(s, 32);
  float inv = 1.f / s;

  #pragma unroll
  for (int j = 0; j < 8; j++) {
    s16x8 o;
    #pragma unroll
    for (int t = 0; t < 8; t++) o[t] = (short)f2bf(f[j * 8 + t] * inv);
    *(s16x8*)(rp + (size_t)j * 512) = o;
  }
}

// ---------------- kernel 6: O = P @ V  (B-operand = V^T, k-major) ----------------
// BM=128 variant -> grid 256 blocks = 1/CU (full GPU despite N=1024).
__global__ __launch_bounds__(512, 2) void k_pv(
    const unsigned short* __restrict__ sc0, const unsigned short* __restrict__ sc1,
    const unsigned short* __restrict__ vt, float* __restrict__ out, int bb)
{
  const int z = blockIdx.z;
  gemm8p<SEQ, 128, 2>(z ? sc1 : sc0, vt + (size_t)(bb + z) * DM * SEQ,
                      out + (size_t)(bb + z) * SEQ * DM, DM, nullptr, 1.f,
                      blockIdx.y * 128, blockIdx.x * 256);
}

extern "C" void kernel_launch(void* const* d_in, const int* in_sizes, int n_in,
                              void* d_out, int out_size, void* d_ws, size_t ws_size,
                              hipStream_t stream) {
  const float* x  = (const float*)d_in[0];
  const float* Wq = (const float*)d_in[1];
  const float* bq = (const float*)d_in[2];
  const float* Wk = (const float*)d_in[3];
  const float* bk = (const float*)d_in[4];
  const float* Wv = (const float*)d_in[5];
  const float* bv = (const float*)d_in[6];
  float* out = (float*)d_out;
  char* ws = (char*)d_ws;

  // ws layout (bytes) — 166 MB proven footprint
  unsigned short* xb = (unsigned short*)(ws);                         // 32 MB; reused as sc0 after qkv
  unsigned short* wb = (unsigned short*)(ws + 33554432);              //  6 MB
  unsigned short* qb = (unsigned short*)(ws + 39845888);              // 32 MB
  unsigned short* kb = (unsigned short*)(ws + 73400320);              // 32 MB
  unsigned short* vb = (unsigned short*)(ws + 106954752);             // 32 MB; reused as sc1 after transpose
  unsigned short* vt = (unsigned short*)(ws + 140509184);             // 32 MB
  unsigned short* sc0 = xb;   // dead after k_qkv
  unsigned short* sc1 = vb;   // dead after k_transpose

  k_conv<<<4096, 256, 0, stream>>>(x, xb, NTOK * DM / 8);
  k_conv<<<512, 256, 0, stream>>>(Wq, wb, DM * DM / 8);
  k_conv<<<512, 256, 0, stream>>>(Wk, wb + DM * DM, DM * DM / 8);
  k_conv<<<512, 256, 0, stream>>>(Wv, wb + 2 * DM * DM, DM * DM / 8);

  k_qkv<<<dim3(4, 64, 3), 512, 0, stream>>>(xb, wb, bq, bk, bv, qb, kb, vb);
  k_transpose<<<dim3(64, 16, 4), 256, 0, stream>>>(vb, vt);

  for (int bb = 0; bb < NB; bb += 2) {
    k_sgemm<<<dim3(16, 16, 2), 512, 0, stream>>>(qb, kb, sc0, sc1, bb);
    k_softmax<<<dim3(1024, 1, 2), 256, 0, stream>>>(sc0, sc1);
    k_pv<<<dim3(4, 32, 2), 512, 0, stream>>>(sc0, sc1, vt, out, bb);
  }
}

// Round 4
// 506.227 us; speedup vs baseline: 1.1818x; 1.1818x over previous
//
#include <hip/hip_runtime.h>
#include <stdint.h>
#include <stddef.h>

#define DM 1024
#define SEQ 4096
#define NB 4
#define NTOK (NB*SEQ)

typedef __attribute__((ext_vector_type(8))) short s16x8;
typedef __attribute__((ext_vector_type(4))) float f32x4;

__device__ __forceinline__ unsigned short f2bf(float f) {
  unsigned int u = __float_as_uint(f);
  u += 0x7FFFu + ((u >> 16) & 1u);   // round-to-nearest-even
  return (unsigned short)(u >> 16);
}

__device__ __forceinline__ f32x4 mfma16(s16x8 a, s16x8 b, f32x4 c) {
  return __builtin_amdgcn_mfma_f32_16x16x32_bf16(a, b, c, 0, 0, 0);
}

__device__ __forceinline__ void gload16(const void* g, void* l) {
  __builtin_amdgcn_global_load_lds((const __attribute__((address_space(1))) unsigned int*)g,
                                   (__attribute__((address_space(3))) unsigned int*)l, 16, 0, 0);
}

// XCD-aware bijective block swizzle (T1): hw id % 8 = XCD; give each XCD a
// contiguous logical range so same-A-panel blocks (consecutive x) share an L2.
// Requires nwg % 8 == 0 (all our GEMM grids satisfy this).
__device__ __forceinline__ void xcd_swz(int gx, int gy, int& x, int& y, int& z) {
  int nwg = gx * gy * gridDim.z;
  int bid = blockIdx.x + gx * (blockIdx.y + gy * blockIdx.z);
  int cpx = nwg >> 3;
  int wg = (bid & 7) * cpx + (bid >> 3);
  x = wg % gx; int t = wg / gx; y = t % gy; z = t / gy;
}

// ---------------- kernel 1: f32 -> bf16 bulk convert ----------------
__global__ void k_conv(const float* __restrict__ s, unsigned short* __restrict__ d, int n8) {
  int i = blockIdx.x * blockDim.x + threadIdx.x;
  int st = gridDim.x * blockDim.x;
  for (; i < n8; i += st) {
    const f32x4* sp = (const f32x4*)s + (size_t)i * 2;
    f32x4 a = sp[0], b = sp[1];
    s16x8 o;
    o[0] = (short)f2bf(a[0]); o[1] = (short)f2bf(a[1]);
    o[2] = (short)f2bf(a[2]); o[3] = (short)f2bf(a[3]);
    o[4] = (short)f2bf(b[0]); o[5] = (short)f2bf(b[1]);
    o[6] = (short)f2bf(b[2]); o[7] = (short)f2bf(b[3]);
    *((s16x8*)d + i) = o;
  }
}

// ---------------- shared GEMM core: C = A @ B^T (both k-major) ----------------
// 128x128 tile, 4 waves (64x64 each), double-buffered LDS, global_load_lds with
// pre-swizzled source (rule #21: inverse-swz source + swz read, XOR involution).
// BK=32: 32 KB LDS -> 4-5 blocks/CU (TLP hides the per-tile vmcnt0 drain).
// BK=64: 64 KB LDS, 2 blocks/CU (proven R2 path; used where block count is low).
// EPI: 0 = bf16 out + bias; 1 = fp16 out * scale; 2 = f32 out.
template<int KD, int BK, int EPI>
__device__ __forceinline__ void gemm_core(
    const unsigned short* __restrict__ A, const unsigned short* __restrict__ B,
    void* __restrict__ outp, int ldc, const float* __restrict__ bias, float scale,
    int mbase, int nbase)
{
  constexpr int NT     = KD / BK;
  constexpr int SLOTS  = BK / 8;        // 16B slots per row (8 or 4)
  constexpr int SMASK  = SLOTS - 1;
  constexpr int PASSES = 128 * SLOTS / 256;  // staging passes per matrix (4 or 2)

  __shared__ unsigned short lds[2][2][128 * BK];
  const int tid = threadIdx.x, lane = tid & 63, wid = tid >> 6;
  const int wr = wid >> 1, wc = wid & 1;
  const int l15 = lane & 15, lg = lane >> 4;

  f32x4 acc[4][4];
  #pragma unroll
  for (int m = 0; m < 4; m++)
    #pragma unroll
    for (int n = 0; n < 4; n++) { acc[m][n][0]=0.f; acc[m][n][1]=0.f; acc[m][n][2]=0.f; acc[m][n][3]=0.f; }

  auto rswz = [](int row) -> int { return (BK == 64) ? (row & 7) : ((row >> 1) & 3); };

  auto stage = [&](int buf, int kt) {
    const int kb_ = kt * BK;
    #pragma unroll
    for (int p = 0; p < PASSES; p++) {
      int s = p * 256 + tid;
      int row = s / SLOTS, sl = (s & SMASK) ^ rswz(row);
      gload16(A + (size_t)(mbase + row) * KD + kb_ + sl * 8, &lds[buf][0][s * 8]);
    }
    #pragma unroll
    for (int p = 0; p < PASSES; p++) {
      int s = p * 256 + tid;
      int row = s / SLOTS, sl = (s & SMASK) ^ rswz(row);
      gload16(B + (size_t)(nbase + row) * KD + kb_ + sl * 8, &lds[buf][1][s * 8]);
    }
  };

  auto compute = [&](int buf) {
    #pragma unroll
    for (int k2 = 0; k2 < BK / 32; k2++) {
      s16x8 af[4], bf[4];
      #pragma unroll
      for (int m = 0; m < 4; m++) {
        int row = wr * 64 + m * 16 + l15;
        int sl = (k2 * 4 + lg) ^ rswz(row);
        af[m] = *(const s16x8*)(&lds[buf][0][0] + row * BK + sl * 8);
      }
      #pragma unroll
      for (int n = 0; n < 4; n++) {
        int row = wc * 64 + n * 16 + l15;
        int sl = (k2 * 4 + lg) ^ rswz(row);
        bf[n] = *(const s16x8*)(&lds[buf][1][0] + row * BK + sl * 8);
      }
      #pragma unroll
      for (int m = 0; m < 4; m++)
        #pragma unroll
        for (int n = 0; n < 4; n++)
          acc[m][n] = mfma16(af[m], bf[n], acc[m][n]);
    }
  };

  stage(0, 0);
  __syncthreads();
  for (int kt = 0; kt < NT; kt++) {
    int cur = kt & 1;
    if (kt < NT - 1) stage(cur ^ 1, kt + 1);
    compute(cur);
    __syncthreads();
  }

  #pragma unroll
  for (int n = 0; n < 4; n++) {
    int col = nbase + wc * 64 + n * 16 + l15;
    float bb = (EPI == 0) ? bias[col] : 0.f;
    #pragma unroll
    for (int m = 0; m < 4; m++) {
      #pragma unroll
      for (int r = 0; r < 4; r++) {
        int row = mbase + wr * 64 + m * 16 + lg * 4 + r;
        float v = acc[m][n][r];
        if (EPI == 0) {
          ((unsigned short*)outp)[(size_t)row * ldc + col] = f2bf(v + bb);
        } else if (EPI == 1) {
          _Float16 h = (_Float16)(v * scale);
          ((unsigned short*)outp)[(size_t)row * ldc + col] = __builtin_bit_cast(unsigned short, h);
        } else {
          ((float*)outp)[(size_t)row * ldc + col] = v;
        }
      }
    }
  }
}

// ---------------- kernel 2: fused QKV projection (BK=32, high occupancy) ----------------
__global__ __launch_bounds__(256, 4) void k_qkv(
    const unsigned short* __restrict__ xb, const unsigned short* __restrict__ wb,
    const float* __restrict__ b0, const float* __restrict__ b1, const float* __restrict__ b2,
    unsigned short* __restrict__ qo, unsigned short* __restrict__ ko, unsigned short* __restrict__ vo)
{
  int x, y, z;
  xcd_swz(8, 128, x, y, z);
  gemm_core<DM, 32, 0>(xb, wb + (size_t)z * DM * DM,
                       (z == 0) ? qo : (z == 1) ? ko : vo, DM,
                       (z == 0) ? b0 : (z == 1) ? b1 : b2, 0.f,
                       y * 128, x * 128);
}

// ---------------- kernel 3: V -> V^T transpose (per batch) ----------------
__global__ void k_transpose(const unsigned short* __restrict__ v, unsigned short* __restrict__ vt) {
  __shared__ unsigned short t[64][65];
  const int b = blockIdx.z;
  const int rbase = blockIdx.x * 64;   // token dim
  const int cbase = blockIdx.y * 64;   // channel dim
  const unsigned short* vb = v + (size_t)b * SEQ * DM;
  unsigned short* vtb = vt + (size_t)b * DM * SEQ;
  const int tid = threadIdx.x;
  #pragma unroll
  for (int it = 0; it < 16; it++) {
    int idx = it * 256 + tid;
    int r = idx >> 6, c = idx & 63;
    t[r][c] = vb[(size_t)(rbase + r) * DM + cbase + c];
  }
  __syncthreads();
  #pragma unroll
  for (int it = 0; it < 16; it++) {
    int idx = it * 256 + tid;
    int oc = idx >> 6, ot = idx & 63;
    vtb[(size_t)(cbase + oc) * SEQ + rbase + ot] = t[ot][oc];
  }
}

// ---------------- kernel 4: scores GEMM  S = Q @ K^T * scale -> fp16 (BK=32) ----------------
__global__ __launch_bounds__(256, 4) void k_sgemm(
    const unsigned short* __restrict__ qb, const unsigned short* __restrict__ kb,
    unsigned short* __restrict__ sc0, unsigned short* __restrict__ sc1, int bb)
{
  int x, y, z;
  xcd_swz(32, 32, x, y, z);
  gemm_core<DM, 32, 1>(qb + (size_t)(bb + z) * SEQ * DM, kb + (size_t)(bb + z) * SEQ * DM,
                       z ? sc1 : sc0, SEQ, nullptr, 0.03125f,
                       y * 128, x * 128);
}

// ---------------- kernel 5: row softmax, in-place fp16 -> normalized bf16 ----------------
__global__ __launch_bounds__(256) void k_softmax(unsigned short* __restrict__ sc0,
                                                 unsigned short* __restrict__ sc1) {
  unsigned short* sc = blockIdx.z ? sc1 : sc0;
  const int row = blockIdx.x * 4 + (threadIdx.x >> 6);
  const int lane = threadIdx.x & 63;
  unsigned short* rp = sc + (size_t)row * SEQ + lane * 8;

  s16x8 v[8];
  #pragma unroll
  for (int j = 0; j < 8; j++) v[j] = *(const s16x8*)(rp + (size_t)j * 512);

  float f[64];
  float m = -1e30f;
  #pragma unroll
  for (int j = 0; j < 8; j++)
    #pragma unroll
    for (int t = 0; t < 8; t++) {
      float x = (float)__builtin_bit_cast(_Float16, (unsigned short)v[j][t]);
      f[j * 8 + t] = x;
      m = fmaxf(m, x);
    }
  m = fmaxf(m, __shfl_xor(m, 1));  m = fmaxf(m, __shfl_xor(m, 2));
  m = fmaxf(m, __shfl_xor(m, 4));  m = fmaxf(m, __shfl_xor(m, 8));
  m = fmaxf(m, __shfl_xor(m, 16)); m = fmaxf(m, __shfl_xor(m, 32));

  float s = 0.f;
  #pragma unroll
  for (int i = 0; i < 64; i++) { f[i] = __expf(f[i] - m); s += f[i]; }
  s += __shfl_xor(s, 1);  s += __shfl_xor(s, 2);  s += __shfl_xor(s, 4);
  s += __shfl_xor(s, 8);  s += __shfl_xor(s, 16); s += __shfl_xor(s, 32);
  float inv = 1.f / s;

  #pragma unroll
  for (int j = 0; j < 8; j++) {
    s16x8 o;
    #pragma unroll
    for (int t = 0; t < 8; t++) o[t] = (short)f2bf(f[j * 8 + t] * inv);
    *(s16x8*)(rp + (size_t)j * 512) = o;
  }
}

// ---------------- kernel 6: O = P @ V  (B-operand = V^T, k-major; BK=64) ----------------
// Only 512 blocks -> 2/CU regardless of LDS; keep BK=64 for per-tile amortization.
__global__ __launch_bounds__(256, 2) void k_pv(
    const unsigned short* __restrict__ sc0, const unsigned short* __restrict__ sc1,
    const unsigned short* __restrict__ vt, float* __restrict__ out, int bb)
{
  int x, y, z;
  xcd_swz(8, 32, x, y, z);
  gemm_core<SEQ, 64, 2>(z ? sc1 : sc0, vt + (size_t)(bb + z) * DM * SEQ,
                        out + (size_t)(bb + z) * SEQ * DM, DM, nullptr, 1.f,
                        y * 128, x * 128);
}

extern "C" void kernel_launch(void* const* d_in, const int* in_sizes, int n_in,
                              void* d_out, int out_size, void* d_ws, size_t ws_size,
                              hipStream_t stream) {
  const float* x  = (const float*)d_in[0];
  const float* Wq = (const float*)d_in[1];
  const float* bq = (const float*)d_in[2];
  const float* Wk = (const float*)d_in[3];
  const float* bk = (const float*)d_in[4];
  const float* Wv = (const float*)d_in[5];
  const float* bv = (const float*)d_in[6];
  float* out = (float*)d_out;
  char* ws = (char*)d_ws;

  // ws layout (bytes) — 166 MB proven footprint
  unsigned short* xb = (unsigned short*)(ws);                         // 32 MB; reused as sc0 after qkv
  unsigned short* wb = (unsigned short*)(ws + 33554432);              //  6 MB
  unsigned short* qb = (unsigned short*)(ws + 39845888);              // 32 MB
  unsigned short* kb = (unsigned short*)(ws + 73400320);              // 32 MB
  unsigned short* vb = (unsigned short*)(ws + 106954752);             // 32 MB; reused as sc1 after transpose
  unsigned short* vt = (unsigned short*)(ws + 140509184);             // 32 MB
  unsigned short* sc0 = xb;   // dead after k_qkv
  unsigned short* sc1 = vb;   // dead after k_transpose

  k_conv<<<4096, 256, 0, stream>>>(x, xb, NTOK * DM / 8);
  k_conv<<<512, 256, 0, stream>>>(Wq, wb, DM * DM / 8);
  k_conv<<<512, 256, 0, stream>>>(Wk, wb + DM * DM, DM * DM / 8);
  k_conv<<<512, 256, 0, stream>>>(Wv, wb + 2 * DM * DM, DM * DM / 8);

  k_qkv<<<dim3(8, 128, 3), 256, 0, stream>>>(xb, wb, bq, bk, bv, qb, kb, vb);
  k_transpose<<<dim3(64, 16, 4), 256, 0, stream>>>(vb, vt);

  for (int bb = 0; bb < NB; bb += 2) {
    k_sgemm<<<dim3(32, 32, 2), 256, 0, stream>>>(qb, kb, sc0, sc1, bb);
    k_softmax<<<dim3(1024, 1, 2), 256, 0, stream>>>(sc0, sc1);
    k_pv<<<dim3(8, 32, 2), 256, 0, stream>>>(sc0, sc1, vt, out, bb);
  }
}